// Round 12
// baseline (34.307 us; speedup 1.0000x reference)
//
#include <hip/hip_runtime.h>
#include <math.h>

namespace {
constexpr int   NTYPES   = 200;
constexpr float RAD10_   = 0.17453292519943295f;
constexpr float RAD30_   = 0.52359877559829882f;
constexpr float RAD150_  = 2.6179938779914944f;
constexpr float RAD180_  = 3.14159265358979323f;
constexpr float CONST_T  = 0.89776110649108887f; // exp(-0.004314*25)

// folded: 332/(8.8*CONST_T), 0.5*332/(88*CONST_T), sqrt(200*0.05/298),
// vk(|c2e|=1)=sqrt(200*ION_CORR/298), vk(0.5)
constexpr float ARG_K   = 42.0237329f;
constexpr float KON_K   = 2.10118664f;
constexpr float KON_SQK = 0.18318583f;
constexpr float VK_AA   = 0.19337050f;
constexpr float VK_MIX  = 0.13673360f;

// rec.w bits: 0..7 at_name, 8..9 chain, 10..18 resnum,
// 19 rc, 20 cz, 21 aa, 22 charged, 23 virtual, 24 dipole0,
// 25 chg_mag (|c|==1), 26 chg_sign (c<0)
constexpr unsigned RC_B   = 1u << 19;
constexpr unsigned CZ_B   = 1u << 20;
constexpr unsigned AA_B   = 1u << 21;
constexpr unsigned CHG_B  = 1u << 22;
constexpr unsigned VIRT_B = 1u << 23;
constexpr unsigned DIP0_B = 1u << 24;
constexpr unsigned MAG_B  = 1u << 25;
constexpr unsigned SGN_B  = 1u << 26;
constexpr unsigned RESCH_M = 0x7FF00u;
constexpr unsigned CHAIN_M = 0x300u;

constexpr int MAX_FILT_WORDS = 3200;   // 102,400 atoms @ 1 bit/atom
}

typedef int   i4v __attribute__((ext_vector_type(4)));
typedef float f4v __attribute__((ext_vector_type(4)));

// Merged prep: 16 B record + 1-bit filter via ballot.
// Filter bit = "atom can EVER contribute": kon-capable (charged & !virtual &
// dipole0) OR arg-capable (cz|rc).  Strict superset of the pair predicate
// (kon energy needs both kon-capable; arg energy needs both in {cz,rc});
// survivors are exactly re-checked from full bits in pe().  ~7% pair pass.
__global__ __launch_bounds__(256) void prep_all(
    const float* __restrict__ coords,
    const float* __restrict__ props,
    const int*   __restrict__ desc,
    float4*      __restrict__ rec,
    unsigned*    __restrict__ filt,
    int nwords, int natoms)
{
    const int idx = blockIdx.x * blockDim.x + threadIdx.x;
    bool interesting = false;
    if (idx < natoms) {
        const int at  = desc[3 * idx];
        const int res = desc[3 * idx + 1];
        const int ch  = desc[3 * idx + 2];
        unsigned bits = (unsigned)at | ((unsigned)ch << 8) | ((unsigned)res << 10);
        if ((at == 10) | (at == 11))       bits |= RC_B;
        if (at == 12)                      bits |= CZ_B;
        if (at == 13)                      bits |= AA_B;
        const float c = props[5 * at + 1];
        if (props[5 * at + 0] == 1.0f)     bits |= CHG_B;
        if (props[5 * at + 2] == 1.0f)     bits |= VIRT_B;
        if (props[5 * at + 3] == 0.0f)     bits |= DIP0_B;
        if (fabsf(c) == 1.0f)              bits |= MAG_B;
        if (c < 0.0f)                      bits |= SGN_B;
        rec[idx] = make_float4(coords[3 * idx], coords[3 * idx + 1],
                               coords[3 * idx + 2], __uint_as_float(bits));
        const bool kon_cap = ((bits & CHG_B) != 0) & ((bits & VIRT_B) == 0) &
                             ((bits & DIP0_B) != 0);
        interesting = kon_cap | ((bits & (CZ_B | RC_B)) != 0);
    }
    const unsigned long long m = __ballot(interesting);
    const unsigned lane = threadIdx.x & 63u;
    if ((lane & 31u) == 0u) {
        const int w = idx >> 5;
        if (w < nwords) filt[w] = (unsigned)(m >> lane);
    }
}

// Everything needed is in two 16 B records (registers). Only the rare ARG
// path touches memory (partners gathers, usually whole-wave execz).
__device__ __forceinline__ float pe(
    const float4 A, const float4 B, int i, int j,
    const float* __restrict__ partners)
{
    const unsigned ba = __float_as_uint(A.w);
    const unsigned bb = __float_as_uint(B.w);

    const float dx = A.x - B.x, dy = A.y - B.y, dz = A.z - B.z;
    const float dist = sqrtf(dx * dx + dy * dy + dz * dz + 1e-12f);
    const bool diff_res = ((ba ^ bb) & RESCH_M) != 0;
    if (!((dist <= 15.0f) & diff_res)) return 0.0f;

    float energy = 0.0f;

    const bool czA = (ba & CZ_B) != 0, czB = (bb & CZ_B) != 0;
    const bool rcA = (ba & RC_B) != 0, rcB = (bb & RC_B) != 0;
    const bool argInv = (czA & (czB | rcB)) | (czB & (czA | rcA));
    if (argInv && (dist >= 3.9f) && (dist <= 4.3f)) {
        const float a0x = partners[6 * i],     a0y = partners[6 * i + 1], a0z = partners[6 * i + 2];
        const float a1x = partners[6 * i + 3], a1y = partners[6 * i + 4], a1z = partners[6 * i + 5];
        const float b0x = partners[6 * j],     b0y = partners[6 * j + 1], b0z = partners[6 * j + 2];
        const float b1x = partners[6 * j + 3], b1y = partners[6 * j + 4], b1z = partners[6 * j + 5];
        const float u1x = a0x - A.x, u1y = a0y - A.y, u1z = a0z - A.z;
        const float v1x = a1x - A.x, v1y = a1y - A.y, v1z = a1z - A.z;
        const float n1x = u1y * v1z - u1z * v1y;
        const float n1y = u1z * v1x - u1x * v1z;
        const float n1z = u1x * v1y - u1y * v1x;
        const float u2x = b0x - B.x, u2y = b0y - B.y, u2z = b0z - B.z;
        const float v2x = b1x - B.x, v2y = b1y - B.y, v2z = b1z - B.z;
        const float n2x = u2y * v2z - u2z * v2y;
        const float n2y = u2z * v2x - u2x * v2z;
        const float n2z = u2x * v2y - u2y * v2x;
        const float nn1 = sqrtf(n1x * n1x + n1y * n1y + n1z * n1z + 1e-12f);
        const float nn2 = sqrtf(n2x * n2x + n2y * n2y + n2z * n2z + 1e-12f);
        const bool  m = (nn1 > 1e-6f) & (nn2 > 1e-6f);
        float cosang = (n1x * n2x + n1y * n2y + n1z * n2z) / (nn1 * nn2);
        cosang = fminf(fmaxf(cosang, -0.999999f), 0.999999f);
        const float ang = acosf(cosang);
        const bool ang_mid_bad = (ang > RAD30_) & (ang < RAD150_);
        if (m & !ang_mid_bad) {
            const float temp_d = 3.0f + fabsf(dist - 4.1f);
            // dist in [3.9,4.3] > RAD150 -> angle-corr branch always
            const float corr = fmaxf((RAD180_ - ang) * (1.0f / RAD10_), 1.0f);
            const bool  arg_arg = ((ba & bb & AA_B) != 0);
            const float c2e = arg_arg ? -1.0f : -0.5f;
            const float vk  = arg_arg ? VK_AA : VK_MIX;
            energy += c2e * ARG_K * expf(-temp_d * vk) /
                      (corr * dist * temp_d * temp_d);
        }
    }

    // kon: charge magnitude/sign from bits (c != 0 <=> CHG flag; radius dead)
    const bool kon = ((ba & bb & CHG_B) != 0) &
                     (((ba | bb) & VIRT_B) == 0) &
                     ((ba & bb & DIP0_B) != 0) &
                     (((ba ^ bb) & CHAIN_M) != 0);
    if (kon) {
        const float tk = fmaxf(dist + dist * dist * (1.0f / 30.0f), 6.0f);
        const int ms = (int)((ba >> 25) & 1u) + (int)((bb >> 25) & 1u);
        const float mag  = (ms == 0) ? 0.25f : ((ms == 1) ? 0.5f : 1.0f);
        const float k_on = KON_SQK * ((ms == 0) ? 0.5f : ((ms == 1) ? 0.70710678f : 1.0f));
        const float e = KON_K * mag * expf(-k_on * (tk - 6.0f)) /
                        (tk * (1.0f + 6.0f * k_on));
        energy += (((ba ^ bb) & SGN_B) != 0) ? -e : e;
    }
    return energy;
}

// Persistent blocks, 1024-pair tiles, PPT=4: per thread 2 int4 pair loads
// (prefetched one tile ahead), 4 LDS filter bits, up to 8 independent float4
// gathers issued together, register compute, one float4 NT store.
__global__ __launch_bounds__(256, 6) void electro_k12(
    const float4*   __restrict__ rec,       // [natoms] 1.6 MB, L2-resident
    const unsigned* __restrict__ filtg,     // [nwords] 12.5 KB -> LDS
    const float*    __restrict__ partners,
    const int*      __restrict__ pairs_raw,
    float*          __restrict__ out,
    int n, int nwords, int tiles)
{
    __shared__ unsigned sfilt[MAX_FILT_WORDS];
    {
        const uint4* fsrc = reinterpret_cast<const uint4*>(filtg);
        const int nv = nwords >> 2;
        for (int t = threadIdx.x; t < nv; t += 256) {
            const uint4 v = fsrc[t];
            sfilt[4 * t]     = v.x;  sfilt[4 * t + 1] = v.y;
            sfilt[4 * t + 2] = v.z;  sfilt[4 * t + 3] = v.w;
        }
        for (int t = (nv << 2) + threadIdx.x; t < nwords; t += 256)
            sfilt[t] = filtg[t];
    }
    __syncthreads();

    const int tid = (int)threadIdx.x;

    auto load_tile = [&](int tile, i4v& a, i4v& b) {
        const int p = (tile << 10) + 4 * tid;     // pairs p..p+3
        if (p + 3 < n) {
            a = __builtin_nontemporal_load(reinterpret_cast<const i4v*>(pairs_raw + 2 * p));
            b = __builtin_nontemporal_load(reinterpret_cast<const i4v*>(pairs_raw + 2 * p + 4));
        } else {
            a = (i4v)0; b = (i4v)0;
            if (p     < n) { a.x = pairs_raw[2*p];     a.y = pairs_raw[2*p + 1]; }
            if (p + 1 < n) { a.z = pairs_raw[2*p + 2]; a.w = pairs_raw[2*p + 3]; }
            if (p + 2 < n) { b.x = pairs_raw[2*p + 4]; b.y = pairs_raw[2*p + 5]; }
        }
    };

    int tile = blockIdx.x;
    if (tile >= tiles) return;
    i4v curA, curB;
    load_tile(tile, curA, curB);

    while (true) {
        const int next = tile + gridDim.x;
        i4v nxtA = (i4v)0, nxtB = (i4v)0;
        if (next < tiles) load_tile(next, nxtA, nxtB);  // hides under this tile

        const int p0 = (tile << 10) + 4 * tid;          // pairs p0..p0+3
        const int i0 = curA.x, j0 = curA.y, i1 = curA.z, j1 = curA.w;
        const int i2 = curB.x, j2 = curB.y, i3 = curB.z, j3 = curB.w;

        const bool f0 = (((sfilt[i0 >> 5] >> (i0 & 31)) & (sfilt[j0 >> 5] >> (j0 & 31))) & 1u) != 0;
        const bool f1 = (((sfilt[i1 >> 5] >> (i1 & 31)) & (sfilt[j1 >> 5] >> (j1 & 31))) & 1u) != 0;
        const bool f2 = (((sfilt[i2 >> 5] >> (i2 & 31)) & (sfilt[j2 >> 5] >> (j2 & 31))) & 1u) != 0;
        const bool f3 = (((sfilt[i3 >> 5] >> (i3 & 31)) & (sfilt[j3 >> 5] >> (j3 & 31))) & 1u) != 0;

        // select-to-zero: failing lanes broadcast line 0 (free)
        const int a0 = f0 ? i0 : 0, b0 = f0 ? j0 : 0;
        const int a1 = f1 ? i1 : 0, b1 = f1 ? j1 : 0;
        const int a2 = f2 ? i2 : 0, b2 = f2 ? j2 : 0;
        const int a3 = f3 ? i3 : 0, b3 = f3 ? j3 : 0;

        // 8 independent gathers, one latency exposure
        const float4 A0 = rec[a0];  const float4 B0 = rec[b0];
        const float4 A1 = rec[a1];  const float4 B1 = rec[b1];
        const float4 A2 = rec[a2];  const float4 B2 = rec[b2];
        const float4 A3 = rec[a3];  const float4 B3 = rec[b3];

        const float e0 = f0 ? pe(A0, B0, i0, j0, partners) : 0.0f;
        const float e1 = f1 ? pe(A1, B1, i1, j1, partners) : 0.0f;
        const float e2 = f2 ? pe(A2, B2, i2, j2, partners) : 0.0f;
        const float e3 = f3 ? pe(A3, B3, i3, j3, partners) : 0.0f;

        if (p0 + 3 < n) {
            f4v r; r.x = e0; r.y = e1; r.z = e2; r.w = e3;
            __builtin_nontemporal_store(r, reinterpret_cast<f4v*>(out + p0));
        } else {
            if (p0     < n) out[p0]     = e0;
            if (p0 + 1 < n) out[p0 + 1] = e1;
            if (p0 + 2 < n) out[p0 + 2] = e2;
        }

        if (next >= tiles) break;
        tile = next;
        curA = nxtA;
        curB = nxtB;
    }
}

// -------- fallback (reference-direct) if d_ws too small / atoms too many --------
__global__ __launch_bounds__(256) void electro_fallback(
    const float* __restrict__ coords, const float* __restrict__ partners,
    const float* __restrict__ props, const int* __restrict__ desc,
    const int2* __restrict__ pairs, float* __restrict__ out, int n)
{
    __shared__ float sp[NTYPES * 5];
    for (int t = threadIdx.x; t < NTYPES * 5; t += blockDim.x) sp[t] = props[t];
    __syncthreads();
    const int stride = gridDim.x * blockDim.x;
    for (int p = blockIdx.x * blockDim.x + threadIdx.x; p < n; p += stride) {
        const int2 ij = pairs[p];
        const int i = ij.x, j = ij.y;
        const int at1 = desc[3 * i], at2 = desc[3 * j];
        const bool rc1 = (at1 == 10) | (at1 == 11);
        const bool rc2 = (at2 == 10) | (at2 == 11);
        const bool argInv = ((at1 == 12) & ((at2 == 12) | rc2)) |
                            ((at2 == 12) & ((at1 == 12) | rc1));
        const float* p1 = &sp[5 * at1];
        const float* p2 = &sp[5 * at2];
        const bool is_charged = ((p1[0] == 1.0f) & (p2[0] == 1.0f)) | argInv;
        float energy = 0.0f;
        if (is_charged) {
            const int res1 = desc[3 * i + 1], ch1 = desc[3 * i + 2];
            const int res2 = desc[3 * j + 1], ch2 = desc[3 * j + 2];
            const float ax = coords[3 * i], ay = coords[3 * i + 1], az = coords[3 * i + 2];
            const float bx = coords[3 * j], by = coords[3 * j + 1], bz = coords[3 * j + 2];
            const float dx = ax - bx, dy = ay - by, dz = az - bz;
            const float dist = sqrtf(dx * dx + dy * dy + dz * dz + 1e-12f);
            const bool diff_res = (res1 != res2) | (ch1 != ch2);
            if ((dist <= 15.0f) & diff_res) {
                if (argInv && (dist >= 3.9f) && (dist <= 4.3f)) {
                    const float a0x = partners[6*i],   a0y = partners[6*i+1], a0z = partners[6*i+2];
                    const float a1x = partners[6*i+3], a1y = partners[6*i+4], a1z = partners[6*i+5];
                    const float b0x = partners[6*j],   b0y = partners[6*j+1], b0z = partners[6*j+2];
                    const float b1x = partners[6*j+3], b1y = partners[6*j+4], b1z = partners[6*j+5];
                    const float u1x=a0x-ax,u1y=a0y-ay,u1z=a0z-az;
                    const float v1x=a1x-ax,v1y=a1y-ay,v1z=a1z-az;
                    const float n1x=u1y*v1z-u1z*v1y, n1y=u1z*v1x-u1x*v1z, n1z=u1x*v1y-u1y*v1x;
                    const float u2x=b0x-bx,u2y=b0y-by,u2z=b0z-bz;
                    const float v2x=b1x-bx,v2y=b1y-by,v2z=b1z-bz;
                    const float n2x=u2y*v2z-u2z*v2y, n2y=u2z*v2x-u2x*v2z, n2z=u2x*v2y-u2y*v2x;
                    const float nn1 = sqrtf(n1x*n1x+n1y*n1y+n1z*n1z+1e-12f);
                    const float nn2 = sqrtf(n2x*n2x+n2y*n2y+n2z*n2z+1e-12f);
                    const bool m = (nn1 > 1e-6f) & (nn2 > 1e-6f);
                    float cosang = (n1x*n2x+n1y*n2y+n1z*n2z)/(nn1*nn2);
                    cosang = fminf(fmaxf(cosang, -0.999999f), 0.999999f);
                    const float ang = acosf(cosang);
                    const bool ang_mid_bad = (ang > RAD30_) & (ang < RAD150_);
                    if (m & !ang_mid_bad) {
                        const float dsafe = fmaxf(dist, 1e-6f);
                        const float argEpss = 332.0f / (dsafe * 8.8f * CONST_T);
                        const float temp_d = 3.0f + fabsf(dist - 4.1f);
                        const float corr_ang = (dist > RAD150_)
                            ? fmaxf((RAD180_ - ang) / RAD10_, 1.0f)
                            : fmaxf(dist / RAD10_, 1.0f);
                        const bool arg_arg = (at1 == 13) & (at2 == 13);
                        const float c2e = arg_arg ? -1.0f : -0.5f;
                        const float vk = sqrtf(200.0f * fabsf(c2e) * (0.02f + 0.05f/1.4f) / 298.0f);
                        energy += (1.0f/corr_ang)*c2e*argEpss*expf(-temp_d*vk)/(temp_d*temp_d);
                    }
                }
                const float c1 = p1[1], c2 = p2[1];
                const bool cc = (c1 != 0.0f) & (c2 != 0.0f) &
                                (p1[2] != 1.0f) & (p2[2] != 1.0f);
                const bool kon_mask = cc & (p1[3] == 0.0f) & (p2[3] == 0.0f) & (ch1 != ch2);
                if (kon_mask) {
                    const float sum_radii = p1[4] + p2[4] - 0.09f;
                    const float dd = fmaxf(dist, sum_radii);
                    const float tk = fmaxf(dd + dd*dd*(1.0f/30.0f), 6.0f);
                    const float k_on = sqrtf(200.0f*fabsf(c1)*fabsf(c2)*0.05f/298.0f);
                    const float first = 332.0f*c1*c2/(88.0f*tk*CONST_T);
                    const float second = expf(-k_on*(tk-6.0f));
                    const float third = 1.0f + k_on*6.0f;
                    energy += 0.5f*first*second/third;
                }
            }
        }
        out[p] = energy;
    }
}

extern "C" void kernel_launch(void* const* d_in, const int* in_sizes, int n_in,
                              void* d_out, int out_size, void* d_ws, size_t ws_size,
                              hipStream_t stream) {
    const float* coords   = (const float*)d_in[0];
    const float* partners = (const float*)d_in[1];
    const float* props    = (const float*)d_in[2];
    const int*   desc     = (const int*)d_in[3];
    const int*   pairs_i  = (const int*)d_in[4];
    float*       out      = (float*)d_out;

    const int natoms = in_sizes[0] / 3;    // 100,000
    const int n      = in_sizes[4] / 2;    // 4,000,000 pairs
    const int nwords = (natoms + 31) / 32; // 3,125

    const size_t rec_bytes  = (size_t)natoms * sizeof(float4);
    const size_t filt_off   = (rec_bytes + 255) & ~(size_t)255;
    const size_t need_bytes = filt_off + (size_t)nwords * sizeof(unsigned);

    if (ws_size >= need_bytes && nwords <= MAX_FILT_WORDS) {
        float4*   rec  = (float4*)d_ws;
        unsigned* filt = (unsigned*)((char*)d_ws + filt_off);
        prep_all<<<(natoms + 255) / 256, 256, 0, stream>>>(
            coords, props, desc, rec, filt, nwords, natoms);
        const int tiles = (n + 1023) / 1024;           // 1024 pairs per tile
        int grid = tiles < 2560 ? tiles : 2560;        // persistent blocks
        electro_k12<<<grid, 256, 0, stream>>>(rec, filt, partners, pairs_i,
                                              out, n, nwords, tiles);
    } else {
        const int block = 256;
        int grid = (n + block - 1) / block;
        if (grid > 2048) grid = 2048;
        electro_fallback<<<grid, block, 0, stream>>>(coords, partners, props,
                                                     desc, (const int2*)pairs_i, out, n);
    }
}

// Round 14
// 29.955 us; speedup vs baseline: 1.1453x; 1.1453x over previous
//
#include <hip/hip_runtime.h>
#include <math.h>

namespace {
constexpr int   NTYPES   = 200;
constexpr float RAD10_   = 0.17453292519943295f;
constexpr float RAD30_   = 0.52359877559829882f;
constexpr float RAD150_  = 2.6179938779914944f;
constexpr float RAD180_  = 3.14159265358979323f;
constexpr float CONST_T  = 0.89776110649108887f; // exp(-0.004314*25)

// folded: 332/(8.8*CONST_T), 0.5*332/(88*CONST_T), sqrt(200*0.05/298),
// vk(|c2e|=1)=sqrt(200*ION_CORR/298), vk(0.5)
constexpr float ARG_K   = 42.0237329f;
constexpr float KON_K   = 2.10118664f;
constexpr float KON_SQK = 0.18318583f;
constexpr float VK_AA   = 0.19337050f;
constexpr float VK_MIX  = 0.13673360f;

// rec.w bits: 0..7 at_name, 8..9 chain, 10..18 resnum,
// 19 rc, 20 cz, 21 aa, 22 charged, 23 virtual, 24 dipole0,
// 25 chg_mag (|c|==1), 26 chg_sign (c<0)
constexpr unsigned RC_B   = 1u << 19;
constexpr unsigned CZ_B   = 1u << 20;
constexpr unsigned AA_B   = 1u << 21;
constexpr unsigned CHG_B  = 1u << 22;
constexpr unsigned VIRT_B = 1u << 23;
constexpr unsigned DIP0_B = 1u << 24;
constexpr unsigned MAG_B  = 1u << 25;
constexpr unsigned SGN_B  = 1u << 26;
constexpr unsigned RESCH_M = 0x7FF00u;
constexpr unsigned CHAIN_M = 0x300u;

constexpr int MAX_FILT_WORDS = 3200;   // 102,400 atoms @ 1 bit/atom
}

typedef int   i4v __attribute__((ext_vector_type(4)));
typedef float f2v __attribute__((ext_vector_type(2)));

// Merged prep: 16 B record + 1-bit filter via ballot.
// Filter bit = "atom can EVER contribute": kon-capable (charged & !virtual &
// dipole0) OR arg-capable (cz|rc).  Strict superset of the pair predicate
// (kon energy needs both kon-capable; arg energy needs both in {cz,rc});
// survivors are exactly re-checked from full bits in pe().  ~7% pair pass.
__global__ __launch_bounds__(256) void prep_all(
    const float* __restrict__ coords,
    const float* __restrict__ props,
    const int*   __restrict__ desc,
    float4*      __restrict__ rec,
    unsigned*    __restrict__ filt,
    int nwords, int natoms)
{
    const int idx = blockIdx.x * blockDim.x + threadIdx.x;
    bool interesting = false;
    if (idx < natoms) {
        const int at  = desc[3 * idx];
        const int res = desc[3 * idx + 1];
        const int ch  = desc[3 * idx + 2];
        unsigned bits = (unsigned)at | ((unsigned)ch << 8) | ((unsigned)res << 10);
        if ((at == 10) | (at == 11))       bits |= RC_B;
        if (at == 12)                      bits |= CZ_B;
        if (at == 13)                      bits |= AA_B;
        const float c = props[5 * at + 1];
        if (props[5 * at + 0] == 1.0f)     bits |= CHG_B;
        if (props[5 * at + 2] == 1.0f)     bits |= VIRT_B;
        if (props[5 * at + 3] == 0.0f)     bits |= DIP0_B;
        if (fabsf(c) == 1.0f)              bits |= MAG_B;
        if (c < 0.0f)                      bits |= SGN_B;
        rec[idx] = make_float4(coords[3 * idx], coords[3 * idx + 1],
                               coords[3 * idx + 2], __uint_as_float(bits));
        const bool kon_cap = ((bits & CHG_B) != 0) & ((bits & VIRT_B) == 0) &
                             ((bits & DIP0_B) != 0);
        interesting = kon_cap | ((bits & (CZ_B | RC_B)) != 0);
    }
    const unsigned long long m = __ballot(interesting);
    const unsigned lane = threadIdx.x & 63u;
    if ((lane & 31u) == 0u) {
        const int w = idx >> 5;
        if (w < nwords) filt[w] = (unsigned)(m >> lane);
    }
}

// Everything needed is in two 16 B records (registers). Only the rare ARG
// path touches memory (partners gathers, usually whole-wave execz).
__device__ __forceinline__ float pe(
    const float4 A, const float4 B, int i, int j,
    const float* __restrict__ partners)
{
    const unsigned ba = __float_as_uint(A.w);
    const unsigned bb = __float_as_uint(B.w);

    const float dx = A.x - B.x, dy = A.y - B.y, dz = A.z - B.z;
    const float dist = sqrtf(dx * dx + dy * dy + dz * dz + 1e-12f);
    const bool diff_res = ((ba ^ bb) & RESCH_M) != 0;
    if (!((dist <= 15.0f) & diff_res)) return 0.0f;

    float energy = 0.0f;

    const bool czA = (ba & CZ_B) != 0, czB = (bb & CZ_B) != 0;
    const bool rcA = (ba & RC_B) != 0, rcB = (bb & RC_B) != 0;
    const bool argInv = (czA & (czB | rcB)) | (czB & (czA | rcA));
    if (argInv && (dist >= 3.9f) && (dist <= 4.3f)) {
        const float a0x = partners[6 * i],     a0y = partners[6 * i + 1], a0z = partners[6 * i + 2];
        const float a1x = partners[6 * i + 3], a1y = partners[6 * i + 4], a1z = partners[6 * i + 5];
        const float b0x = partners[6 * j],     b0y = partners[6 * j + 1], b0z = partners[6 * j + 2];
        const float b1x = partners[6 * j + 3], b1y = partners[6 * j + 4], b1z = partners[6 * j + 5];
        const float u1x = a0x - A.x, u1y = a0y - A.y, u1z = a0z - A.z;
        const float v1x = a1x - A.x, v1y = a1y - A.y, v1z = a1z - A.z;
        const float n1x = u1y * v1z - u1z * v1y;
        const float n1y = u1z * v1x - u1x * v1z;
        const float n1z = u1x * v1y - u1y * v1x;
        const float u2x = b0x - B.x, u2y = b0y - B.y, u2z = b0z - B.z;
        const float v2x = b1x - B.x, v2y = b1y - B.y, v2z = b1z - B.z;
        const float n2x = u2y * v2z - u2z * v2y;
        const float n2y = u2z * v2x - u2x * v2z;
        const float n2z = u2x * v2y - u2y * v2x;
        const float nn1 = sqrtf(n1x * n1x + n1y * n1y + n1z * n1z + 1e-12f);
        const float nn2 = sqrtf(n2x * n2x + n2y * n2y + n2z * n2z + 1e-12f);
        const bool  m = (nn1 > 1e-6f) & (nn2 > 1e-6f);
        float cosang = (n1x * n2x + n1y * n2y + n1z * n2z) / (nn1 * nn2);
        cosang = fminf(fmaxf(cosang, -0.999999f), 0.999999f);
        const float ang = acosf(cosang);
        const bool ang_mid_bad = (ang > RAD30_) & (ang < RAD150_);
        if (m & !ang_mid_bad) {
            const float temp_d = 3.0f + fabsf(dist - 4.1f);
            // dist in [3.9,4.3] > RAD150 -> angle-corr branch always
            const float corr = fmaxf((RAD180_ - ang) * (1.0f / RAD10_), 1.0f);
            const bool  arg_arg = ((ba & bb & AA_B) != 0);
            const float c2e = arg_arg ? -1.0f : -0.5f;
            const float vk  = arg_arg ? VK_AA : VK_MIX;
            energy += c2e * ARG_K * expf(-temp_d * vk) /
                      (corr * dist * temp_d * temp_d);
        }
    }

    // kon: charge magnitude/sign from bits (c != 0 <=> CHG flag; radius dead)
    const bool kon = ((ba & bb & CHG_B) != 0) &
                     (((ba | bb) & VIRT_B) == 0) &
                     ((ba & bb & DIP0_B) != 0) &
                     (((ba ^ bb) & CHAIN_M) != 0);
    if (kon) {
        const float tk = fmaxf(dist + dist * dist * (1.0f / 30.0f), 6.0f);
        const int ms = (int)((ba >> 25) & 1u) + (int)((bb >> 25) & 1u);
        const float mag  = (ms == 0) ? 0.25f : ((ms == 1) ? 0.5f : 1.0f);
        const float k_on = KON_SQK * ((ms == 0) ? 0.5f : ((ms == 1) ? 0.70710678f : 1.0f));
        const float e = KON_K * mag * expf(-k_on * (tk - 6.0f)) /
                        (tk * (1.0f + 6.0f * k_on));
        energy += (((ba ^ bb) & SGN_B) != 0) ? -e : e;
    }
    return energy;
}

// Round-11 structure (best so far): persistent blocks, 512-pair tiles, PPT=2,
// software-pipelined NT pair loads, NT float2 stores. Only change vs r11:
// the tighter filter bit (isolated).
__global__ __launch_bounds__(256, 6) void electro_k13(
    const float4*   __restrict__ rec,       // [natoms] 1.6 MB, L2-resident
    const unsigned* __restrict__ filtg,     // [nwords] 12.5 KB -> LDS
    const float*    __restrict__ partners,
    const int*      __restrict__ pairs_raw,
    float*          __restrict__ out,
    int n, int nwords, int tiles)
{
    __shared__ unsigned sfilt[MAX_FILT_WORDS];
    {
        const uint4* fsrc = reinterpret_cast<const uint4*>(filtg);
        const int nv = nwords >> 2;
        for (int t = threadIdx.x; t < nv; t += 256) {
            const uint4 v = fsrc[t];
            sfilt[4 * t]     = v.x;  sfilt[4 * t + 1] = v.y;
            sfilt[4 * t + 2] = v.z;  sfilt[4 * t + 3] = v.w;
        }
        for (int t = (nv << 2) + threadIdx.x; t < nwords; t += 256)
            sfilt[t] = filtg[t];
    }
    __syncthreads();

    const int tid = (int)threadIdx.x;

    auto load_tile = [&](int tile) -> i4v {
        const int p = (tile << 9) + 2 * tid;
        if (p + 1 < n)
            return __builtin_nontemporal_load(
                reinterpret_cast<const i4v*>(pairs_raw + 2 * p));
        i4v r = (i4v)0;
        if (p < n) { r.x = pairs_raw[2 * p]; r.y = pairs_raw[2 * p + 1]; }
        return r;
    };

    int tile = blockIdx.x;
    if (tile >= tiles) return;
    i4v cur = load_tile(tile);

    while (true) {
        const int next = tile + gridDim.x;
        i4v nxt = (i4v)0;
        if (next < tiles) nxt = load_tile(next);   // prefetch: hides under current tile

        const int p0 = (tile << 9) + 2 * tid;      // pairs p0, p0+1
        const int i0 = cur.x, j0 = cur.y, i1 = cur.z, j1 = cur.w;

        const bool f0 = (((sfilt[i0 >> 5] >> (i0 & 31)) & (sfilt[j0 >> 5] >> (j0 & 31))) & 1u) != 0;
        const bool f1 = (((sfilt[i1 >> 5] >> (i1 & 31)) & (sfilt[j1 >> 5] >> (j1 & 31))) & 1u) != 0;

        // select-to-zero: failing lanes broadcast line 0 (free)
        const int a0 = f0 ? i0 : 0, b0 = f0 ? j0 : 0;
        const int a1 = f1 ? i1 : 0, b1 = f1 ? j1 : 0;

        const float4 A0 = rec[a0];
        const float4 B0 = rec[b0];
        const float4 A1 = rec[a1];
        const float4 B1 = rec[b1];

        const float e0 = f0 ? pe(A0, B0, i0, j0, partners) : 0.0f;
        const float e1 = f1 ? pe(A1, B1, i1, j1, partners) : 0.0f;

        if (p0 + 1 < n) {
            f2v r; r.x = e0; r.y = e1;
            __builtin_nontemporal_store(r, reinterpret_cast<f2v*>(out + p0));
        } else if (p0 < n) {
            out[p0] = e0;
        }

        if (next >= tiles) break;
        tile = next;
        cur  = nxt;
    }
}

// -------- fallback (reference-direct) if d_ws too small / atoms too many --------
__global__ __launch_bounds__(256) void electro_fallback(
    const float* __restrict__ coords, const float* __restrict__ partners,
    const float* __restrict__ props, const int* __restrict__ desc,
    const int2* __restrict__ pairs, float* __restrict__ out, int n)
{
    __shared__ float sp[NTYPES * 5];
    for (int t = threadIdx.x; t < NTYPES * 5; t += blockDim.x) sp[t] = props[t];
    __syncthreads();
    const int stride = gridDim.x * blockDim.x;
    for (int p = blockIdx.x * blockDim.x + threadIdx.x; p < n; p += stride) {
        const int2 ij = pairs[p];
        const int i = ij.x, j = ij.y;
        const int at1 = desc[3 * i], at2 = desc[3 * j];
        const bool rc1 = (at1 == 10) | (at1 == 11);
        const bool rc2 = (at2 == 10) | (at2 == 11);
        const bool argInv = ((at1 == 12) & ((at2 == 12) | rc2)) |
                            ((at2 == 12) & ((at1 == 12) | rc1));
        const float* p1 = &sp[5 * at1];
        const float* p2 = &sp[5 * at2];
        const bool is_charged = ((p1[0] == 1.0f) & (p2[0] == 1.0f)) | argInv;
        float energy = 0.0f;
        if (is_charged) {
            const int res1 = desc[3 * i + 1], ch1 = desc[3 * i + 2];
            const int res2 = desc[3 * j + 1], ch2 = desc[3 * j + 2];
            const float ax = coords[3 * i], ay = coords[3 * i + 1], az = coords[3 * i + 2];
            const float bx = coords[3 * j], by = coords[3 * j + 1], bz = coords[3 * j + 2];
            const float dx = ax - bx, dy = ay - by, dz = az - bz;
            const float dist = sqrtf(dx * dx + dy * dy + dz * dz + 1e-12f);
            const bool diff_res = (res1 != res2) | (ch1 != ch2);
            if ((dist <= 15.0f) & diff_res) {
                if (argInv && (dist >= 3.9f) && (dist <= 4.3f)) {
                    const float a0x = partners[6*i],   a0y = partners[6*i+1], a0z = partners[6*i+2];
                    const float a1x = partners[6*i+3], a1y = partners[6*i+4], a1z = partners[6*i+5];
                    const float b0x = partners[6*j],   b0y = partners[6*j+1], b0z = partners[6*j+2];
                    const float b1x = partners[6*j+3], b1y = partners[6*j+4], b1z = partners[6*j+5];
                    const float u1x=a0x-ax,u1y=a0y-ay,u1z=a0z-az;
                    const float v1x=a1x-ax,v1y=a1y-ay,v1z=a1z-az;
                    const float n1x=u1y*v1z-u1z*v1y, n1y=u1z*v1x-u1x*v1z, n1z=u1x*v1y-u1y*v1x;
                    const float u2x=b0x-bx,u2y=b0y-by,u2z=b0z-bz;
                    const float v2x=b1x-bx,v2y=b1y-by,v2z=b1z-bz;
                    const float n2x=u2y*v2z-u2z*v2y, n2y=u2z*v2x-u2x*v2z, n2z=u2x*v2y-u2y*v2x;
                    const float nn1 = sqrtf(n1x*n1x+n1y*n1y+n1z*n1z+1e-12f);
                    const float nn2 = sqrtf(n2x*n2x+n2y*n2y+n2z*n2z+1e-12f);
                    const bool m = (nn1 > 1e-6f) & (nn2 > 1e-6f);
                    float cosang = (n1x*n2x+n1y*n2y+n1z*n2z)/(nn1*nn2);
                    cosang = fminf(fmaxf(cosang, -0.999999f), 0.999999f);
                    const float ang = acosf(cosang);
                    const bool ang_mid_bad = (ang > RAD30_) & (ang < RAD150_);
                    if (m & !ang_mid_bad) {
                        const float dsafe = fmaxf(dist, 1e-6f);
                        const float argEpss = 332.0f / (dsafe * 8.8f * CONST_T);
                        const float temp_d = 3.0f + fabsf(dist - 4.1f);
                        const float corr_ang = (dist > RAD150_)
                            ? fmaxf((RAD180_ - ang) / RAD10_, 1.0f)
                            : fmaxf(dist / RAD10_, 1.0f);
                        const bool arg_arg = (at1 == 13) & (at2 == 13);
                        const float c2e = arg_arg ? -1.0f : -0.5f;
                        const float vk = sqrtf(200.0f * fabsf(c2e) * (0.02f + 0.05f/1.4f) / 298.0f);
                        energy += (1.0f/corr_ang)*c2e*argEpss*expf(-temp_d*vk)/(temp_d*temp_d);
                    }
                }
                const float c1 = p1[1], c2 = p2[1];
                const bool cc = (c1 != 0.0f) & (c2 != 0.0f) &
                                (p1[2] != 1.0f) & (p2[2] != 1.0f);
                const bool kon_mask = cc & (p1[3] == 0.0f) & (p2[3] == 0.0f) & (ch1 != ch2);
                if (kon_mask) {
                    const float sum_radii = p1[4] + p2[4] - 0.09f;
                    const float dd = fmaxf(dist, sum_radii);
                    const float tk = fmaxf(dd + dd*dd*(1.0f/30.0f), 6.0f);
                    const float k_on = sqrtf(200.0f*fabsf(c1)*fabsf(c2)*0.05f/298.0f);
                    const float first = 332.0f*c1*c2/(88.0f*tk*CONST_T);
                    const float second = expf(-k_on*(tk-6.0f));
                    const float third = 1.0f + k_on*6.0f;
                    energy += 0.5f*first*second/third;
                }
            }
        }
        out[p] = energy;
    }
}

extern "C" void kernel_launch(void* const* d_in, const int* in_sizes, int n_in,
                              void* d_out, int out_size, void* d_ws, size_t ws_size,
                              hipStream_t stream) {
    const float* coords   = (const float*)d_in[0];
    const float* partners = (const float*)d_in[1];
    const float* props    = (const float*)d_in[2];
    const int*   desc     = (const int*)d_in[3];
    const int*   pairs_i  = (const int*)d_in[4];
    float*       out      = (float*)d_out;

    const int natoms = in_sizes[0] / 3;    // 100,000
    const int n      = in_sizes[4] / 2;    // 4,000,000 pairs
    const int nwords = (natoms + 31) / 32; // 3,125

    const size_t rec_bytes  = (size_t)natoms * sizeof(float4);
    const size_t filt_off   = (rec_bytes + 255) & ~(size_t)255;
    const size_t need_bytes = filt_off + (size_t)nwords * sizeof(unsigned);

    if (ws_size >= need_bytes && nwords <= MAX_FILT_WORDS) {
        float4*   rec  = (float4*)d_ws;
        unsigned* filt = (unsigned*)((char*)d_ws + filt_off);
        prep_all<<<(natoms + 255) / 256, 256, 0, stream>>>(
            coords, props, desc, rec, filt, nwords, natoms);
        const int tiles = (n + 511) / 512;             // 512 pairs per tile
        int grid = tiles < 2560 ? tiles : 2560;        // persistent blocks
        electro_k13<<<grid, 256, 0, stream>>>(rec, filt, partners, pairs_i,
                                              out, n, nwords, tiles);
    } else {
        const int block = 256;
        int grid = (n + block - 1) / block;
        if (grid > 2048) grid = 2048;
        electro_fallback<<<grid, block, 0, stream>>>(coords, partners, props,
                                                     desc, (const int2*)pairs_i, out, n);
    }
}